// Round 6
// baseline (483.736 us; speedup 1.0000x reference)
//
#include <hip/hip_runtime.h>

// LuGre friction cell, B=4096 x T=2048 serial steps, S=1, H=64.
// Round 6: round 5 spent ~90 of 185 issue-cyc/step on the v-only path,
// executed by 16 redundant lanes (one wave -> only 4 seqs). Split:
//   pass 0 (coef): quartic-in-sz Chebyshev coeffs of -DT*sigma0 at 256 v-nodes.
//   pass 1 (prep): 1 thread per (b,t) step -- one wave covers 64 steps (16x
//     de-redundancy), full occupancy. Emits 9 Horner-ready floats per step
//     (f0..f4 = -DT*c_i(v)*avg, k, q, sv, fs) into SoA streams in d_ws.
//   pass 2 (seq):  serial recurrence, 16 redundant lanes/seq, 1024 waves =
//     1 wave/SIMD. Zero LDS / zero transcendentals: 9 dwordx4 loads per
//     4-step batch, depth-4 register pipeline (~520+ cyc prefetch distance,
//     streams are mostly L3-resident), then a pure-FMA chain:
//     Horner(4) -> e=xd(1+xd/2) -> szn -> med3 clip -> F.
// Falls back to the proven round-5 single-kernel path if ws_size < 288 MiB.

#define DT 1e-3f
#define NV 256
#define VMINF (-6.6f)
#define VMAXF (6.6f)
#define ZAF   (2.56f)   // Chebyshev half-range in sz (sz is clipped to +-F_s <= 2.5)

// ---- pass 0: per-v-node quartic (in sz) coefficients of -DT*sigma0 ---------
__global__ __launch_bounds__(256) void coef_kernel(
    const float* __restrict__ W1,   // [2,64]
    const float* __restrict__ b1,   // [64]
    const float* __restrict__ W2,   // [64]
    const float* __restrict__ b2,   // [1]
    float4* __restrict__ tabA,      // [NV] (c0,c1,c2,c3) * -DT
    float*  __restrict__ tabB)      // [NV] c4 * -DT
{
    const int iv = threadIdx.x;     // single block of 256
    const float v = VMINF + iv * ((VMAXF - VMINF) / (NV - 1));

    const float pn = 0.95105651629f * ZAF;   // cos(pi/10)*A
    const float qn = 0.58778525229f * ZAF;   // cos(3pi/10)*A
    const float nodes[5] = { pn, -pn, qn, -qn, 0.f };
    float f[5];
#pragma unroll
    for (int j = 0; j < 5; ++j) {
        const float szv = nodes[j];
        float y = b2[0];
        for (int h = 0; h < 64; ++h) {
            const float pre = fmaf(v, W1[h], fmaf(szv, W1[64 + h], b1[h]));
            y = fmaf(W2[h], tanhf(pre), y);
        }
        f[j] = fmaxf(y, 0.f) + log1pf(expf(-fabsf(y)));   // softplus(y)
    }
    const float P = pn * pn, Q = qn * qn;
    const float c0 = f[4];
    const float ep = 0.5f * (f[0] + f[1]) - c0;
    const float eq = 0.5f * (f[2] + f[3]) - c0;
    const float op = 0.5f * (f[0] - f[1]);
    const float oq = 0.5f * (f[2] - f[3]);
    const float invPQ = 1.f / (P - Q);
    const float c4 = (ep / P - eq / Q) * invPQ;
    const float c2 = ep / P - c4 * P;
    const float c3 = (op / pn - oq / qn) * invPQ;
    const float c1 = op / pn - c3 * P;
    tabA[iv] = make_float4(-DT * c0, -DT * c1, -DT * c2, -DT * c3);
    tabB[iv] = -DT * c4;
}

// ---- pass 1: per-step v-only precompute, 1 thread per (b,t) ----------------
__global__ __launch_bounds__(256) void prep_kernel(
    const float* __restrict__ x,       // [B*T, 3]
    const float* __restrict__ sigma1,
    const float* __restrict__ sigma2,
    const float* __restrict__ alpha_p,
    const float* __restrict__ vs_p,
    const float4* __restrict__ tabA,   // [NV]
    const float*  __restrict__ tabB,   // [NV]
    float* __restrict__ st,            // 9 SoA streams, each N floats
    long N)
{
    __shared__ float4 sA[NV];
    __shared__ float  sB[NV];
    sA[threadIdx.x] = tabA[threadIdx.x];
    sB[threadIdx.x] = tabB[threadIdx.x];
    __syncthreads();

    const long idx = (long)blockIdx.x * blockDim.x + threadIdx.x;
    if (idx >= N) return;

    const float LOG2E = 1.4426950408889634f;
    const float s1v    = fabsf(sigma1[0]);
    const float s2v    = fabsf(sigma2[0]);
    const float s12    = s1v + s2v;
    const float alpha  = alpha_p[0];
    const float inv_vs = 1.0f / vs_p[0];
    const float SVC    = (NV - 1) / (VMAXF - VMINF);
    const float VOFF   = -VMINF * SVC;    // 127.5
    const float IMAX   = 254.999f;

    const float v  = x[3 * idx + 0];
    const float fc = x[3 * idx + 1];
    const float fs = x[3 * idx + 2];

    const float av = fabsf(v);
    const float u  = av * inv_vs;
    const float lg = __builtin_amdgcn_logf(u);            // log2(u); u=0 -> -inf
    const float pw = __builtin_amdgcn_exp2f(alpha * lg);  // u^alpha (u=0 -> 0)
    const float w_ = __builtin_amdgcn_exp2f(-LOG2E * pw); // exp(-u^alpha)
    const float g  = fmaf(fs - fc, w_, fc);
    const float k  = copysignf(g, v);
    const float avg = av * __builtin_amdgcn_rcpf(g);      // |v|/g
    const float q  = s1v * avg;
    const float sv = s12 * v;

    const float fvr = __builtin_amdgcn_fmed3f(fmaf(v, SVC, VOFF), 0.f, IMAX);
    const float fvf = floorf(fvr);
    const float fr  = fvr - fvf;
    const int   iv  = (int)fvf;
    const float4 A0 = sA[iv], A1 = sA[iv + 1];
    const float  B0 = sB[iv], B1 = sB[iv + 1];
    const float e0 = fmaf(fr, A1.x - A0.x, A0.x);
    const float e1 = fmaf(fr, A1.y - A0.y, A0.y);
    const float e2 = fmaf(fr, A1.z - A0.z, A0.z);
    const float e3 = fmaf(fr, A1.w - A0.w, A0.w);
    const float e4 = fmaf(fr, B1 - B0, B0);

    st[0 * N + idx] = e0 * avg;   // f0 (xd = Horner(f, sz))
    st[1 * N + idx] = e1 * avg;
    st[2 * N + idx] = e2 * avg;
    st[3 * N + idx] = e3 * avg;
    st[4 * N + idx] = e4 * avg;
    st[5 * N + idx] = k;
    st[6 * N + idx] = q;
    st[7 * N + idx] = sv;
    st[8 * N + idx] = fs;
}

// ---- pass 2: serial recurrence, pure streaming + FMA -----------------------
__global__ __launch_bounds__(256) void seq_kernel(
    const float* __restrict__ st,   // 9 SoA streams
    float* __restrict__ out,        // [B, T]
    int B, int T, long N)
{
    const int tid  = blockIdx.x * blockDim.x + threadIdx.x;
    const int lane = tid & 15;
    const int b    = tid >> 4;
    if (b >= B) return;

    const long base = (long)b * T;
    const float4* sp[9];
#pragma unroll
    for (int s = 0; s < 9; ++s) sp[s] = (const float4*)(st + (long)s * N + base);
    float* __restrict__ outb = out + base;

    float sz = 0.f, Fkeep = 0.f;
    const int NB = T / 4;           // 512 batches

    float4 P[4][9];                 // depth-4 register pipeline
#pragma unroll
    for (int d = 0; d < 4; ++d)
#pragma unroll
        for (int s = 0; s < 9; ++s) P[d][s] = sp[s][d];

    for (int n = 0; n < NB; n += 4) {
#pragma unroll
        for (int p = 0; p < 4; ++p) {
            const int t0 = 4 * (n + p);
            const float* F0 = (const float*)&P[p][0];
            const float* F1 = (const float*)&P[p][1];
            const float* F2 = (const float*)&P[p][2];
            const float* F3 = (const float*)&P[p][3];
            const float* F4 = (const float*)&P[p][4];
            const float* KK = (const float*)&P[p][5];
            const float* QQ = (const float*)&P[p][6];
            const float* SV = (const float*)&P[p][7];
            const float* FS = (const float*)&P[p][8];
#pragma unroll
            for (int j = 0; j < 4; ++j) {
                const int tt = t0 + j;
                const float xd = fmaf(fmaf(fmaf(fmaf(F4[j], sz, F3[j]), sz, F2[j]), sz, F1[j]), sz, F0[j]);
                const float e  = xd * fmaf(xd, 0.5f, 1.0f);     // exp(xd)-1, |xd|<~0.02
                const float szn = fmaf(e, sz - KK[j], sz);      // pre-clip sz
                const float szc = __builtin_amdgcn_fmed3f(szn, -FS[j], FS[j]);
                const float F   = fmaf(-QQ[j], szn, SV[j] + szc);
                sz = szc;
                if (lane == (tt & 15)) Fkeep = F;               // static after unroll
                if ((tt & 15) == 15) outb[tt - 15 + lane] = Fkeep;
            }
            // refill slot p with batch n+p+4 (~4 batches of work ahead of use)
            const int nb = min(n + p + 4, NB - 1);
#pragma unroll
            for (int s = 0; s < 9; ++s) P[p][s] = sp[s][nb];
        }
    }
}

// ---- fallback: proven round-5 single-kernel path ---------------------------
struct Pre { float e0, e1, e2, e3, e4, avg, k, q, sv, fs; };

__global__ __launch_bounds__(256) void lugre_kernel(
    const float* __restrict__ x,
    const float* __restrict__ sigma1,
    const float* __restrict__ sigma2,
    const float* __restrict__ alpha_p,
    const float* __restrict__ vs_p,
    const float4* __restrict__ tabA,
    const float*  __restrict__ tabB,
    float* __restrict__ out,
    int B, int T)
{
    __shared__ float4 sA[NV];
    __shared__ float  sB[NV];
    sA[threadIdx.x] = tabA[threadIdx.x];
    sB[threadIdx.x] = tabB[threadIdx.x];
    __syncthreads();

    const int tid  = blockIdx.x * blockDim.x + threadIdx.x;
    const int lane = tid & 15;
    const int b    = tid >> 4;
    if (b >= B) return;

    const float LOG2E = 1.4426950408889634f;
    const float s1v    = fabsf(sigma1[0]);
    const float s2v    = fabsf(sigma2[0]);
    const float s12    = s1v + s2v;
    const float alpha  = alpha_p[0];
    const float inv_vs = 1.0f / vs_p[0];
    const float SVC    = (NV - 1) / (VMAXF - VMINF);
    const float VOFF   = -VMINF * SVC;
    const float IMAX   = 254.999f;

    const float4* __restrict__ xb4 = (const float4*)(x + (size_t)b * T * 3);
    float* __restrict__ outb = out + (size_t)b * T;

    float sz = 0.f, Fkeep = 0.f;

    auto mkpre = [&](float v, float fc, float fs) {
        Pre r;
        const float av = fabsf(v);
        const float u  = av * inv_vs;
        const float lg = __builtin_amdgcn_logf(u);
        const float pw = __builtin_amdgcn_exp2f(alpha * lg);
        const float w_ = __builtin_amdgcn_exp2f(-LOG2E * pw);
        const float g  = fmaf(fs - fc, w_, fc);
        r.k   = copysignf(g, v);
        r.avg = av * __builtin_amdgcn_rcpf(g);
        r.q   = s1v * r.avg;
        r.sv  = s12 * v;
        r.fs  = fs;
        const float fvr = __builtin_amdgcn_fmed3f(fmaf(v, SVC, VOFF), 0.f, IMAX);
        const float fvf = floorf(fvr);
        const float fr  = fvr - fvf;
        const int   iv  = (int)fvf;
        const float4 A0 = sA[iv], A1 = sA[iv + 1];
        const float  Bc0 = sB[iv], Bc1 = sB[iv + 1];
        r.e0 = fmaf(fr, A1.x - A0.x, A0.x);
        r.e1 = fmaf(fr, A1.y - A0.y, A0.y);
        r.e2 = fmaf(fr, A1.z - A0.z, A0.z);
        r.e3 = fmaf(fr, A1.w - A0.w, A0.w);
        r.e4 = fmaf(fr, Bc1 - Bc0, Bc0);
        return r;
    };

    auto chain = [&](const Pre& P, int tt) {
        const float h  = fmaf(fmaf(fmaf(fmaf(P.e4, sz, P.e3), sz, P.e2), sz, P.e1), sz, P.e0);
        const float xd = h * P.avg;
        const float d  = fmaf(xd, fmaf(xd, 0.5f, 1.f), 1.f);
        const float szn = fmaf(d, sz - P.k, P.k);
        const float szc = __builtin_amdgcn_fmed3f(szn, -P.fs, P.fs);
        const float F   = fmaf(-P.q, szn, P.sv + szc);
        sz = szc;
        if (lane == (tt & 15)) Fkeep = F;
        if ((tt & 15) == 15) outb[tt - 15 + lane] = Fkeep;
    };

    const int lastb = T / 4 - 1;
    float4 A0x = xb4[0], A1x = xb4[1], A2x = xb4[2];
    float4 B0x = xb4[3], B1x = xb4[4], B2x = xb4[5];
    float4 C0x = xb4[6], C1x = xb4[7], C2x = xb4[8];

    Pre pre[4];
    pre[0] = mkpre(A0x.x, A0x.y, A0x.z);
    pre[1] = mkpre(A0x.w, A1x.x, A1x.y);
    pre[2] = mkpre(A1x.z, A1x.w, A2x.x);
    pre[3] = mkpre(A2x.y, A2x.z, A2x.w);

#pragma unroll 4
    for (int n = 0; n < T / 4; ++n) {
        const int nb = min(n + 3, lastb);
        const float4 L0 = xb4[3 * nb], L1 = xb4[3 * nb + 1], L2 = xb4[3 * nb + 2];

        Pre pn0 = mkpre(B0x.x, B0x.y, B0x.z);
        Pre pn1 = mkpre(B0x.w, B1x.x, B1x.y);
        Pre pn2 = mkpre(B1x.z, B1x.w, B2x.x);
        Pre pn3 = mkpre(B2x.y, B2x.z, B2x.w);

        const int t0 = 4 * n;
        chain(pre[0], t0);
        chain(pre[1], t0 + 1);
        chain(pre[2], t0 + 2);
        chain(pre[3], t0 + 3);

        B0x = C0x; B1x = C1x; B2x = C2x;
        C0x = L0;  C1x = L1;  C2x = L2;
        pre[0] = pn0; pre[1] = pn1; pre[2] = pn2; pre[3] = pn3;
    }
}

extern "C" void kernel_launch(void* const* d_in, const int* in_sizes, int n_in,
                              void* d_out, int out_size, void* d_ws, size_t ws_size,
                              hipStream_t stream) {
    const float* x   = (const float*)d_in[0];
    const float* s1  = (const float*)d_in[1];
    const float* s2  = (const float*)d_in[2];
    const float* al  = (const float*)d_in[3];
    const float* vs  = (const float*)d_in[4];
    const float* W1  = (const float*)d_in[5];
    const float* b1  = (const float*)d_in[6];
    const float* W2  = (const float*)d_in[7];
    const float* b2  = (const float*)d_in[8];
    float* out = (float*)d_out;

    float4* tabA = (float4*)d_ws;                       // 4096 B
    float*  tabB = (float*)((char*)d_ws + NV * 16);     // 1024 B
    float*  st   = (float*)((char*)d_ws + 8192);        // 9 SoA streams

    const int T = 2048;
    const int B = out_size / T;          // 4096
    const long N = (long)B * T;          // 8388608

    coef_kernel<<<1, 256, 0, stream>>>(W1, b1, W2, b2, tabA, tabB);

    const size_t need = 8192 + (size_t)9 * N * sizeof(float);  // ~288 MiB
    if (ws_size >= need) {
        const int gp = (int)((N + 255) / 256);
        prep_kernel<<<gp, 256, 0, stream>>>(x, s1, s2, al, vs, tabA, tabB, st, N);
        seq_kernel<<<(B * 16) / 256, 256, 0, stream>>>(st, out, B, T, N);
    } else {
        // fallback: proven round-5 single-kernel path (needs only 5 KB of ws)
        const int threads = B * 16;
        lugre_kernel<<<(threads + 255) / 256, 256, 0, stream>>>(
            x, s1, s2, al, vs, tabA, tabB, out, B, T);
    }
}